// Round 2
// baseline (642.090 us; speedup 1.0000x reference)
//
#include <hip/hip_runtime.h>
#include <hip/hip_bf16.h>
#include <hip/hip_fp16.h>

typedef _Float16 f16;
typedef __attribute__((ext_vector_type(8))) _Float16 f16x8;
typedef __attribute__((ext_vector_type(4))) _Float16 f16x4;
typedef __attribute__((ext_vector_type(4))) float f32x4;

#define BQ 16
#define SQ 1024
#define HQ 512
#define MQ (BQ*SQ)          // 16384 rows total
#define PLANE ((size_t)MQ*512)

// ---- workspace layout (bytes). Aliasing:
//   ANORM aliases XF16[0:32MB]   (XF16 planes 0-1 dead after gate GEMMs)
//   HN    aliases XF16[32MB:48MB] (plane 2; first written in layer 0)
//   YT    aliases T              (T dead after gate GEMMs)
#define OFF_WG1T 0ul
#define OFF_WG2T 524288ul
#define OFF_W0T  1048576ul
#define OFF_W1T  2621440ul
#define OFF_W2T  3145728ul
#define OFF_WENT 3670016ul
#define OFF_ENTS 3672064ul
#define OFF_DSI  3868672ul
#define OFF_XF16 3934208ul
#define OFF_ANORM OFF_XF16
#define OFF_HN   (OFF_XF16 + 33554432ul)
#define OFF_T    71043072ul
#define OFF_YT   OFF_T
#define OFF_HCAT 104597504ul
// total = 104597504 + 50331648 = 154929152 bytes (~148 MB)

// ---------------- weight prep: fold gate algebra, transpose to [N][K], cast f16
__global__ __launch_bounds__(256) void k_prep(
    const float* __restrict__ gW, const float* __restrict__ W0,
    const float* __restrict__ W1, const float* __restrict__ W2,
    f16* __restrict__ Wg1t, f16* __restrict__ Wg2t, f16* __restrict__ W0t,
    f16* __restrict__ W1t, f16* __restrict__ W2t, float* __restrict__ went)
{
    int i = blockIdx.x * 256 + threadIdx.x;      // grid covers 1536*512
    if (i < 1536*512) {
        int n = i & 511, k = i >> 9;             // k < 1536
        W0t[(size_t)n*1536 + k] = (f16)W0[(size_t)k*512 + n];
    }
    if (i < 512*512) {
        int n = i >> 9, k = i & 511;
        float wa = gW[(size_t)k*512 + n];
        float wb = gW[(size_t)(512 + k)*512 + n];
        float wr = gW[(size_t)(1024 + k)*512 + n];
        Wg1t[(size_t)n*512 + k] = (f16)(wa + wb - 0.5f*wr);
        Wg2t[(size_t)n*512 + k] = (f16)(0.5f*wr);
        W1t[(size_t)n*512 + k]  = (f16)W1[(size_t)k*512 + n];
        W2t[(size_t)n*512 + k]  = (f16)W2[(size_t)k*512 + n];
    }
    if (i < 512) went[i] = gW[(size_t)1536*512 + i];
}

// ---------------- entropy per row per modality + f16 casts + sum plane
__global__ __launch_bounds__(256) void k_ent(
    const float* __restrict__ t, const float* __restrict__ a, const float* __restrict__ v,
    f16* __restrict__ xf, float* __restrict__ ents)
{
    int wave = threadIdx.x >> 6, lane = threadIdx.x & 63;
    int row = blockIdx.x * 4 + wave;
    const float* ptrs[3] = {t, a, v};
    float sum8[8];
#pragma unroll
    for (int j = 0; j < 8; j++) sum8[j] = 0.f;
#pragma unroll
    for (int m = 0; m < 3; m++) {
        const float4* p = (const float4*)(ptrs[m] + (size_t)row*512);
        float4 x0 = p[lane*2], x1 = p[lane*2 + 1];
        float xs[8] = {x0.x,x0.y,x0.z,x0.w,x1.x,x1.y,x1.z,x1.w};
        float s = 0.f;
#pragma unroll
        for (int j = 0; j < 8; j++) s += fabsf(xs[j]);
#pragma unroll
        for (int off = 32; off; off >>= 1) s += __shfl_xor(s, off);
        float inv = 1.f / (s + 1e-10f);
        float e = 0.f;
#pragma unroll
        for (int j = 0; j < 8; j++) { float fn = fabsf(xs[j])*inv; e += fn*__logf(fn + 1e-10f); }
#pragma unroll
        for (int off = 32; off; off >>= 1) e += __shfl_xor(e, off);
        if (lane == 0) ents[m*MQ + row] = -e;
        f16x8 o;
#pragma unroll
        for (int j = 0; j < 8; j++) o[j] = (f16)xs[j];
        *(f16x8*)(xf + ((size_t)m*MQ + row)*512 + lane*8) = o;
#pragma unroll
        for (int j = 0; j < 8; j++) sum8[j] += xs[j];
    }
    f16x8 o;
#pragma unroll
    for (int j = 0; j < 8; j++) o[j] = (f16)sum8[j];
    *(f16x8*)(xf + ((size_t)3*MQ + row)*512 + lane*8) = o;
}

// ---------------- dsi = (rowsum(0.5*(sp+tg)) + 1 + eps)^-1/2
__global__ __launch_bounds__(256) void k_dsi(
    const float* __restrict__ sp, const float* __restrict__ tg, float* __restrict__ dsi)
{
    int wave = threadIdx.x >> 6, lane = threadIdx.x & 63;
    int row = blockIdx.x * 4 + wave;     // 0..16383 (b*1024+i)
    const float4* p1 = (const float4*)(sp + (size_t)row*1024);
    const float4* p2 = (const float4*)(tg + (size_t)row*1024);
    float s = 0.f;
#pragma unroll
    for (int c = 0; c < 4; c++) {
        float4 x = p1[c*64 + lane], y = p2[c*64 + lane];
        s += x.x + x.y + x.z + x.w + y.x + y.y + y.z + y.w;
    }
#pragma unroll
    for (int off = 32; off; off >>= 1) s += __shfl_xor(s, off);
    if (lane == 0) dsi[row] = 1.f / sqrtf(0.5f*s + 1.f + 1e-10f);
}

// ---------------- norm_adj build (f16)
__global__ __launch_bounds__(256) void k_anorm(
    const float* __restrict__ sp, const float* __restrict__ tg,
    const float* __restrict__ dsi, f16* __restrict__ an)
{
    size_t t = (size_t)blockIdx.x*256 + threadIdx.x;   // 4 elems per thread
    int j4 = (int)(t & 255) * 4;
    int i  = (int)(t >> 8) & 1023;
    int b  = (int)(t >> 18);
    size_t base = ((size_t)b << 20) + (size_t)i*1024 + j4;
    float4 x = *(const float4*)(sp + base);
    float4 y = *(const float4*)(tg + base);
    float4 dj = *(const float4*)(dsi + b*1024 + j4);
    float di = dsi[b*1024 + i];
    float v0 = 0.5f*(x.x + y.x) + (i == j4+0 ? 1.f : 0.f);
    float v1 = 0.5f*(x.y + y.y) + (i == j4+1 ? 1.f : 0.f);
    float v2 = 0.5f*(x.z + y.z) + (i == j4+2 ? 1.f : 0.f);
    float v3 = 0.5f*(x.w + y.w) + (i == j4+3 ? 1.f : 0.f);
    f16x4 o;
    o[0] = (f16)(di*v0*dj.x); o[1] = (f16)(di*v1*dj.y);
    o[2] = (f16)(di*v2*dj.z); o[3] = (f16)(di*v3*dj.w);
    *(f16x4*)(an + base) = o;
}

// ---------------- NT GEMM, 128x128 tile, 4 waves, mfma 16x16x32_f16, fp32 acc
// A [M][K] row-major f16 (lda==K), Bt [512][K] row-major f16 (ldb==K)
// MODE 0: write f32 (T buffer)          grid (M/128, 4)
// MODE 1: gate epilogue -> Hcat f16     grid (128, 4)
// MODE 2: write f16 transposed -> Yt    grid (128, 4)
// MODE 3: batched adj: +bias, relu ->Hn grid (8, 4, 16)
template<int MODE>
__global__ __launch_bounds__(256) void k_gemm(
    const f16* __restrict__ A, const f16* __restrict__ Bt, int K,
    float* __restrict__ fOut,
    const float* __restrict__ Tbuf, const float* __restrict__ entS,
    const float* __restrict__ went, const float* __restrict__ gb,
    const float* __restrict__ featf, f16* __restrict__ hOut, int hColOff,
    const float* __restrict__ bias)
{
    __shared__ f16 As[128][40];   // +16B pad: 80B row stride, 16B aligned
    __shared__ f16 Bs[128][40];
    int tid = threadIdx.x;
    int lane = tid & 63, wave = tid >> 6;
    int wr = wave >> 1, wc = wave & 1;
    int m0 = blockIdx.x * 128, n0 = blockIdx.y * 128;
    int z = blockIdx.z;
    if constexpr (MODE == 3) {
        A  += (size_t)z * (1024*1024);
        Bt += (size_t)z * (512*1024);
    }
    int sr = tid >> 1, sc = (tid & 1) * 16;
    const f16* Ap = A  + (size_t)(m0 + sr)*K + sc;
    const f16* Bp = Bt + (size_t)(n0 + sr)*K + sc;
    f32x4 acc[4][4];
#pragma unroll
    for (int mi = 0; mi < 4; mi++)
#pragma unroll
        for (int ni = 0; ni < 4; ni++) acc[mi][ni] = (f32x4){0.f,0.f,0.f,0.f};
    int g = lane >> 4, r = lane & 15;
    for (int kt = 0; kt < K; kt += 32) {
        f16x8 av0 = *(const f16x8*)(Ap + kt);
        f16x8 av1 = *(const f16x8*)(Ap + kt + 8);
        f16x8 bv0 = *(const f16x8*)(Bp + kt);
        f16x8 bv1 = *(const f16x8*)(Bp + kt + 8);
        __syncthreads();
        *(f16x8*)&As[sr][sc]     = av0;
        *(f16x8*)&As[sr][sc + 8] = av1;
        *(f16x8*)&Bs[sr][sc]     = bv0;
        *(f16x8*)&Bs[sr][sc + 8] = bv1;
        __syncthreads();
        f16x8 af[4], bf[4];
#pragma unroll
        for (int mi = 0; mi < 4; mi++) af[mi] = *(const f16x8*)&As[wr*64 + mi*16 + r][g*8];
#pragma unroll
        for (int ni = 0; ni < 4; ni++) bf[ni] = *(const f16x8*)&Bs[wc*64 + ni*16 + r][g*8];
#pragma unroll
        for (int mi = 0; mi < 4; mi++)
#pragma unroll
            for (int ni = 0; ni < 4; ni++)
                acc[mi][ni] = __builtin_amdgcn_mfma_f32_16x16x32_f16(af[mi], bf[ni], acc[mi][ni], 0, 0, 0);
    }
    // epilogue: C frag mapping col = lane&15, row = (lane>>4)*4 + j   [m89-verified]
#pragma unroll
    for (int mi = 0; mi < 4; mi++) {
        int row0 = m0 + wr*64 + mi*16 + g*4;
#pragma unroll
        for (int ni = 0; ni < 4; ni++) {
            int col = n0 + wc*64 + ni*16 + r;
            f32x4 v = acc[mi][ni];
            if constexpr (MODE == 0) {
#pragma unroll
                for (int j = 0; j < 4; j++)
                    fOut[(size_t)(row0 + j)*512 + col] = v[j];
            } else if constexpr (MODE == 1) {
                float wcol = went[col], gbc = gb[col];
#pragma unroll
                for (int j = 0; j < 4; j++) {
                    int row = row0 + j;
                    float val = v[j] + Tbuf[(size_t)row*512 + col] + entS[row]*wcol + gbc;
                    float gate = 1.f / (1.f + __expf(-val));
                    float o = gate * featf[(size_t)row*512 + col];
                    hOut[(size_t)row*1536 + hColOff + col] = (f16)o;
                }
            } else if constexpr (MODE == 2) {
                int bb = row0 >> 10, ml = row0 & 1023;
                f16x4 h4;
#pragma unroll
                for (int j = 0; j < 4; j++) h4[j] = (f16)v[j];
                *(f16x4*)(hOut + (((size_t)(bb*512 + col)) << 10) + ml) = h4;
            } else {
                float bcol = bias[col];
#pragma unroll
                for (int j = 0; j < 4; j++) {
                    float o = v[j] + bcol;
                    o = o > 0.f ? o : 0.f;
                    hOut[(size_t)(z*1024 + row0 + j)*512 + col] = (f16)o;
                }
            }
        }
    }
}

// ---------------- classifier: out = h3 @ Wc + bc  (f32 on VALU, tiny)
__global__ __launch_bounds__(256) void k_cls(
    const f16* __restrict__ h, const float* __restrict__ Wc,
    const float* __restrict__ bc, float* __restrict__ out)
{
    int wave = threadIdx.x >> 6, lane = threadIdx.x & 63;
    int row = blockIdx.x * 4 + wave;
    f16x8 hv = *(const f16x8*)(h + (size_t)row*512 + lane*8);
    float acc[7];
#pragma unroll
    for (int c = 0; c < 7; c++) acc[c] = 0.f;
#pragma unroll
    for (int j = 0; j < 8; j++) {
        float x = (float)hv[j];
        const float* wrow = Wc + (size_t)(lane*8 + j)*7;
#pragma unroll
        for (int c = 0; c < 7; c++) acc[c] += x * wrow[c];
    }
#pragma unroll
    for (int off = 32; off; off >>= 1)
#pragma unroll
        for (int c = 0; c < 7; c++) acc[c] += __shfl_xor(acc[c], off);
    if (lane == 0) {
#pragma unroll
        for (int c = 0; c < 7; c++) out[(size_t)row*7 + c] = acc[c] + bc[c];
    }
}

extern "C" void kernel_launch(void* const* d_in, const int* in_sizes, int n_in,
                              void* d_out, int out_size, void* d_ws, size_t ws_size,
                              hipStream_t stream) {
    (void)in_sizes; (void)n_in; (void)out_size; (void)ws_size;
    const float* text   = (const float*)d_in[0];
    const float* audio  = (const float*)d_in[1];
    const float* visual = (const float*)d_in[2];
    const float* spg    = (const float*)d_in[3];
    const float* tmg    = (const float*)d_in[4];
    const float* gW     = (const float*)d_in[6];
    const float* gb     = (const float*)d_in[7];
    const float* W0     = (const float*)d_in[8];
    const float* b0     = (const float*)d_in[9];
    const float* W1     = (const float*)d_in[10];
    const float* b1     = (const float*)d_in[11];
    const float* W2     = (const float*)d_in[12];
    const float* b2     = (const float*)d_in[13];
    const float* Wc     = (const float*)d_in[14];
    const float* bc     = (const float*)d_in[15];

    char* ws = (char*)d_ws;
    f16*   Wg1t = (f16*)(ws + OFF_WG1T);
    f16*   Wg2t = (f16*)(ws + OFF_WG2T);
    f16*   W0t  = (f16*)(ws + OFF_W0T);
    f16*   W1t  = (f16*)(ws + OFF_W1T);
    f16*   W2t  = (f16*)(ws + OFF_W2T);
    float* went = (float*)(ws + OFF_WENT);
    float* ents = (float*)(ws + OFF_ENTS);
    float* dsi  = (float*)(ws + OFF_DSI);
    f16*   xf   = (f16*)(ws + OFF_XF16);
    f16*   an   = (f16*)(ws + OFF_ANORM);
    f16*   hn   = (f16*)(ws + OFF_HN);
    float* Tbuf = (float*)(ws + OFF_T);
    f16*   yt   = (f16*)(ws + OFF_YT);
    f16*   hcat = (f16*)(ws + OFF_HCAT);
    float* outp = (float*)d_out;

    dim3 blk(256);
    // prep + elementwise
    k_prep<<<3072, blk, 0, stream>>>(gW, W0, W1, W2, Wg1t, Wg2t, W0t, W1t, W2t, went);
    k_ent<<<4096, blk, 0, stream>>>(text, audio, visual, xf, ents);
    k_dsi<<<4096, blk, 0, stream>>>(spg, tmg, dsi);

    // T = Fsum @ Wg2
    k_gemm<0><<<dim3(128,4), blk, 0, stream>>>(xf + 3*PLANE, Wg2t, 512,
        Tbuf, nullptr, nullptr, nullptr, nullptr, nullptr, nullptr, 0, nullptr);
    // gates -> Hcat (reads original f32 feats as multiplicand)
    k_gemm<1><<<dim3(128,4), blk, 0, stream>>>(xf + 0*PLANE, Wg1t, 512,
        nullptr, Tbuf, ents + 0*MQ, went, gb, text,   hcat, 0,    nullptr);
    k_gemm<1><<<dim3(128,4), blk, 0, stream>>>(xf + 1*PLANE, Wg1t, 512,
        nullptr, Tbuf, ents + 1*MQ, went, gb, audio,  hcat, 512,  nullptr);
    k_gemm<1><<<dim3(128,4), blk, 0, stream>>>(xf + 2*PLANE, Wg1t, 512,
        nullptr, Tbuf, ents + 2*MQ, went, gb, visual, hcat, 1024, nullptr);

    // norm_adj (aliases XF16 planes 0-1 — safe now that gates are done)
    k_anorm<<<16384, blk, 0, stream>>>(spg, tmg, dsi, an);

    // layer 0
    k_gemm<2><<<dim3(128,4), blk, 0, stream>>>(hcat, W0t, 1536,
        nullptr, nullptr, nullptr, nullptr, nullptr, nullptr, yt, 0, nullptr);
    k_gemm<3><<<dim3(8,4,16), blk, 0, stream>>>(an, yt, 1024,
        nullptr, nullptr, nullptr, nullptr, nullptr, nullptr, hn, 0, b0);
    // layer 1
    k_gemm<2><<<dim3(128,4), blk, 0, stream>>>(hn, W1t, 512,
        nullptr, nullptr, nullptr, nullptr, nullptr, nullptr, yt, 0, nullptr);
    k_gemm<3><<<dim3(8,4,16), blk, 0, stream>>>(an, yt, 1024,
        nullptr, nullptr, nullptr, nullptr, nullptr, nullptr, hn, 0, b1);
    // layer 2
    k_gemm<2><<<dim3(128,4), blk, 0, stream>>>(hn, W2t, 512,
        nullptr, nullptr, nullptr, nullptr, nullptr, nullptr, yt, 0, nullptr);
    k_gemm<3><<<dim3(8,4,16), blk, 0, stream>>>(an, yt, 1024,
        nullptr, nullptr, nullptr, nullptr, nullptr, nullptr, hn, 0, b2);

    // classifier
    k_cls<<<4096, blk, 0, stream>>>(hn, Wc, bc, outp);
}

// Round 4
// 551.821 us; speedup vs baseline: 1.1636x; 1.1636x over previous
//
#include <hip/hip_runtime.h>
#include <hip/hip_bf16.h>
#include <hip/hip_fp16.h>

typedef _Float16 f16;
typedef __attribute__((ext_vector_type(8))) _Float16 f16x8;
typedef __attribute__((ext_vector_type(4))) _Float16 f16x4;
typedef __attribute__((ext_vector_type(4))) float f32x4;
typedef __attribute__((address_space(1))) const unsigned int gu32;
typedef __attribute__((address_space(3))) unsigned int lu32;

#define BQ 16
#define SQ 1024
#define HQ 512
#define MQ (BQ*SQ)          // 16384 rows total
#define PLANE ((size_t)MQ*512)

// ---- workspace layout (bytes). Aliasing:
//   ANORM aliases XF16 planes 0-1 (dead after gate GEMMs)
//   HN    aliases XF16 plane 2 (first written in layer 0, after gates)
//   YT    aliases T    (T dead after gate GEMMs)
#define OFF_WG1T 0ul
#define OFF_WG2T 524288ul
#define OFF_W0T  1048576ul
#define OFF_W1T  2621440ul
#define OFF_W2T  3145728ul
#define OFF_WENT 3670016ul
#define OFF_ENTS 3672064ul
#define OFF_DSI  3868672ul
#define OFF_XF16 3934208ul
#define OFF_ANORM OFF_XF16
#define OFF_HN   (OFF_XF16 + 33554432ul)
#define OFF_T    71043072ul
#define OFF_YT   OFF_T
#define OFF_HCAT 104597504ul
// total = 104597504 + 50331648 = 154929152 bytes (~148 MB)

// async global->LDS, 16B per lane; LDS dest is wave-uniform base + lane*16
__device__ __forceinline__ void gl16(f16* lds, const f16* g) {
    __builtin_amdgcn_global_load_lds(
        (gu32*)(const __attribute__((address_space(1))) f16*)g,
        (lu32*)(__attribute__((address_space(3))) f16*)lds, 16, 0, 0);
}

// ---------------- weight prep: fold gate algebra, transpose to [N][K], cast f16
__global__ __launch_bounds__(256) void k_prep(
    const float* __restrict__ gW, const float* __restrict__ W0,
    const float* __restrict__ W1, const float* __restrict__ W2,
    f16* __restrict__ Wg1t, f16* __restrict__ Wg2t, f16* __restrict__ W0t,
    f16* __restrict__ W1t, f16* __restrict__ W2t, float* __restrict__ went)
{
    int i = blockIdx.x * 256 + threadIdx.x;      // grid covers 1536*512
    if (i < 1536*512) {
        int n = i & 511, k = i >> 9;             // k < 1536
        W0t[(size_t)n*1536 + k] = (f16)W0[(size_t)k*512 + n];
    }
    if (i < 512*512) {
        int n = i >> 9, k = i & 511;
        float wa = gW[(size_t)k*512 + n];
        float wb = gW[(size_t)(512 + k)*512 + n];
        float wr = gW[(size_t)(1024 + k)*512 + n];
        Wg1t[(size_t)n*512 + k] = (f16)(wa + wb - 0.5f*wr);
        Wg2t[(size_t)n*512 + k] = (f16)(0.5f*wr);
        W1t[(size_t)n*512 + k]  = (f16)W1[(size_t)k*512 + n];
        W2t[(size_t)n*512 + k]  = (f16)W2[(size_t)k*512 + n];
    }
    if (i < 512) went[i] = gW[(size_t)1536*512 + i];
}

// ---------------- entropy per row per modality + f16 casts + sum plane
__global__ __launch_bounds__(256) void k_ent(
    const float* __restrict__ t, const float* __restrict__ a, const float* __restrict__ v,
    f16* __restrict__ xf, float* __restrict__ ents)
{
    int wave = threadIdx.x >> 6, lane = threadIdx.x & 63;
    int row = blockIdx.x * 4 + wave;
    const float* ptrs[3] = {t, a, v};
    float sum8[8];
#pragma unroll
    for (int j = 0; j < 8; j++) sum8[j] = 0.f;
#pragma unroll
    for (int m = 0; m < 3; m++) {
        const float4* p = (const float4*)(ptrs[m] + (size_t)row*512);
        float4 x0 = p[lane*2], x1 = p[lane*2 + 1];
        float xs[8] = {x0.x,x0.y,x0.z,x0.w,x1.x,x1.y,x1.z,x1.w};
        float s = 0.f;
#pragma unroll
        for (int j = 0; j < 8; j++) s += fabsf(xs[j]);
#pragma unroll
        for (int off = 32; off; off >>= 1) s += __shfl_xor(s, off);
        float inv = 1.f / (s + 1e-10f);
        float e = 0.f;
#pragma unroll
        for (int j = 0; j < 8; j++) { float fn = fabsf(xs[j])*inv; e += fn*__logf(fn + 1e-10f); }
#pragma unroll
        for (int off = 32; off; off >>= 1) e += __shfl_xor(e, off);
        if (lane == 0) ents[m*MQ + row] = -e;
        f16x8 o;
#pragma unroll
        for (int j = 0; j < 8; j++) o[j] = (f16)xs[j];
        *(f16x8*)(xf + ((size_t)m*MQ + row)*512 + lane*8) = o;
#pragma unroll
        for (int j = 0; j < 8; j++) sum8[j] += xs[j];
    }
    f16x8 o;
#pragma unroll
    for (int j = 0; j < 8; j++) o[j] = (f16)sum8[j];
    *(f16x8*)(xf + ((size_t)3*MQ + row)*512 + lane*8) = o;
}

// ---------------- dsi = (rowsum(0.5*(sp+tg)) + 1 + eps)^-1/2
__global__ __launch_bounds__(256) void k_dsi(
    const float* __restrict__ sp, const float* __restrict__ tg, float* __restrict__ dsi)
{
    int wave = threadIdx.x >> 6, lane = threadIdx.x & 63;
    int row = blockIdx.x * 4 + wave;     // 0..16383 (b*1024+i)
    const float4* p1 = (const float4*)(sp + (size_t)row*1024);
    const float4* p2 = (const float4*)(tg + (size_t)row*1024);
    float s = 0.f;
#pragma unroll
    for (int c = 0; c < 4; c++) {
        float4 x = p1[c*64 + lane], y = p2[c*64 + lane];
        s += x.x + x.y + x.z + x.w + y.x + y.y + y.z + y.w;
    }
#pragma unroll
    for (int off = 32; off; off >>= 1) s += __shfl_xor(s, off);
    if (lane == 0) dsi[row] = 1.f / sqrtf(0.5f*s + 1.f + 1e-10f);
}

// ---------------- norm_adj build (f16)
__global__ __launch_bounds__(256) void k_anorm(
    const float* __restrict__ sp, const float* __restrict__ tg,
    const float* __restrict__ dsi, f16* __restrict__ an)
{
    size_t t = (size_t)blockIdx.x*256 + threadIdx.x;   // 4 elems per thread
    int j4 = (int)(t & 255) * 4;
    int i  = (int)(t >> 8) & 1023;
    int b  = (int)(t >> 18);
    size_t base = ((size_t)b << 20) + (size_t)i*1024 + j4;
    float4 x = *(const float4*)(sp + base);
    float4 y = *(const float4*)(tg + base);
    float4 dj = *(const float4*)(dsi + b*1024 + j4);
    float di = dsi[b*1024 + i];
    float v0 = 0.5f*(x.x + y.x) + (i == j4+0 ? 1.f : 0.f);
    float v1 = 0.5f*(x.y + y.y) + (i == j4+1 ? 1.f : 0.f);
    float v2 = 0.5f*(x.z + y.z) + (i == j4+2 ? 1.f : 0.f);
    float v3 = 0.5f*(x.w + y.w) + (i == j4+3 ? 1.f : 0.f);
    f16x4 o;
    o[0] = (f16)(di*v0*dj.x); o[1] = (f16)(di*v1*dj.y);
    o[2] = (f16)(di*v2*dj.z); o[3] = (f16)(di*v3*dj.w);
    *(f16x4*)(an + base) = o;
}

// ---------------- NT GEMM, 128x128 tile, 4 waves, mfma 16x16x32_f16, fp32 acc
// BK=64 (128B rows), global_load_lds(16B) staging, XOR-swizzled chunks (T2):
//   LDS slot (row, c) holds global chunk c^(row&7); reader uses c=(kk*4+g)^(row&7)
//   -> each bank-quad hit by exactly 8 of 64 lanes = minimum = conflict-free.
// A [M][K] row-major f16, Bt [512][K] row-major f16.
// MODE 0: write f16 (T buffer)          grid (128, 4)
// MODE 1: gate epilogue -> Hcat f16     grid (128, 4)
// MODE 2: write f16 transposed -> Yt    grid (128, 4)
// MODE 3: batched adj: +bias, relu ->Hn grid (8, 4, 16)
template<int MODE>
__global__ __launch_bounds__(256) void k_gemm(
    const f16* __restrict__ A, const f16* __restrict__ Bt, int K,
    const f16* __restrict__ Tbuf, const float* __restrict__ entS,
    const float* __restrict__ went, const float* __restrict__ gb,
    const f16* __restrict__ featf, f16* __restrict__ hOut, int hColOff,
    const float* __restrict__ bias)
{
    __shared__ f16 As[128*64];   // [row][chunk(8x16B)] linear, 128B row stride
    __shared__ f16 Bs[128*64];
    int tid = threadIdx.x;
    int lane = tid & 63, wave = tid >> 6;
    int wr = wave >> 1, wc = wave & 1;
    int m0 = blockIdx.x * 128, n0 = blockIdx.y * 128;
    int z = blockIdx.z;
    if constexpr (MODE == 3) {
        A  += (size_t)z * (1024*1024);
        Bt += (size_t)z * (512*1024);
    }
    // staging source (pre-swizzled): lane covers row m0+wave*32+j*8+(lane>>3),
    // 16B chunk (lane&7)^(lane>>3) of the 128B k-window
    int lrow = lane >> 3;
    int swz  = (lane & 7) ^ lrow;
    const f16* pA = A  + (size_t)(m0 + wave*32 + lrow)*K + swz*8;
    const f16* pB = Bt + (size_t)(n0 + wave*32 + lrow)*K + swz*8;
    f16* lA = As + (wave*4)*512;   // wave-uniform LDS base, phase j adds j*512
    f16* lB = Bs + (wave*4)*512;

    f32x4 acc[4][4];
#pragma unroll
    for (int mi = 0; mi < 4; mi++)
#pragma unroll
        for (int ni = 0; ni < 4; ni++) acc[mi][ni] = (f32x4){0.f,0.f,0.f,0.f};
    int g = lane >> 4, r = lane & 15;

    for (int kt = 0; kt < K; kt += 64) {
        __syncthreads();                      // prev reads done before overwrite
#pragma unroll
        for (int j = 0; j < 4; j++) {
            gl16(lA + j*512, pA + (size_t)(j*8)*K + kt);
            gl16(lB + j*512, pB + (size_t)(j*8)*K + kt);
        }
        __syncthreads();                      // vmcnt(0) drain -> data in LDS
#pragma unroll
        for (int kk = 0; kk < 2; kk++) {
            f16x8 af[4], bf[4];
#pragma unroll
            for (int mi = 0; mi < 4; mi++) {
                int row = wr*64 + mi*16 + r;
                int ch = (kk*4 + g) ^ (row & 7);
                af[mi] = *(const f16x8*)&As[row*64 + ch*8];
            }
#pragma unroll
            for (int ni = 0; ni < 4; ni++) {
                int row = wc*64 + ni*16 + r;
                int ch = (kk*4 + g) ^ (row & 7);
                bf[ni] = *(const f16x8*)&Bs[row*64 + ch*8];
            }
#pragma unroll
            for (int mi = 0; mi < 4; mi++)
#pragma unroll
                for (int ni = 0; ni < 4; ni++)
                    acc[mi][ni] = __builtin_amdgcn_mfma_f32_16x16x32_f16(af[mi], bf[ni], acc[mi][ni], 0, 0, 0);
        }
    }
    // epilogue: C frag mapping col = lane&15, row = (lane>>4)*4 + j   [m89-verified]
#pragma unroll
    for (int mi = 0; mi < 4; mi++) {
        int row0 = m0 + wr*64 + mi*16 + g*4;
#pragma unroll
        for (int ni = 0; ni < 4; ni++) {
            int col = n0 + wc*64 + ni*16 + r;
            f32x4 v = acc[mi][ni];
            if constexpr (MODE == 0) {
#pragma unroll
                for (int j = 0; j < 4; j++)
                    hOut[(size_t)(row0 + j)*512 + col] = (f16)v[j];
            } else if constexpr (MODE == 1) {
                float wcol = went[col], gbc = gb[col];
#pragma unroll
                for (int j = 0; j < 4; j++) {
                    int row = row0 + j;
                    float val = v[j] + (float)Tbuf[(size_t)row*512 + col] + entS[row]*wcol + gbc;
                    float gate = 1.f / (1.f + __expf(-val));
                    float o = gate * (float)featf[(size_t)row*512 + col];
                    hOut[(size_t)row*1536 + hColOff + col] = (f16)o;
                }
            } else if constexpr (MODE == 2) {
                int bb = row0 >> 10, ml = row0 & 1023;
                f16x4 h4;
#pragma unroll
                for (int j = 0; j < 4; j++) h4[j] = (f16)v[j];
                *(f16x4*)(hOut + (((size_t)(bb*512 + col)) << 10) + ml) = h4;
            } else {
                float bcol = bias[col];
#pragma unroll
                for (int j = 0; j < 4; j++) {
                    float o = v[j] + bcol;
                    o = o > 0.f ? o : 0.f;
                    hOut[(size_t)(z*1024 + row0 + j)*512 + col] = (f16)o;
                }
            }
        }
    }
}

// ---------------- classifier: out = h3 @ Wc + bc  (f32 on VALU, tiny)
__global__ __launch_bounds__(256) void k_cls(
    const f16* __restrict__ h, const float* __restrict__ Wc,
    const float* __restrict__ bc, float* __restrict__ out)
{
    int wave = threadIdx.x >> 6, lane = threadIdx.x & 63;
    int row = blockIdx.x * 4 + wave;
    f16x8 hv = *(const f16x8*)(h + (size_t)row*512 + lane*8);
    float acc[7];
#pragma unroll
    for (int c = 0; c < 7; c++) acc[c] = 0.f;
#pragma unroll
    for (int j = 0; j < 8; j++) {
        float x = (float)hv[j];
        const float* wrow = Wc + (size_t)(lane*8 + j)*7;
#pragma unroll
        for (int c = 0; c < 7; c++) acc[c] += x * wrow[c];
    }
#pragma unroll
    for (int off = 32; off; off >>= 1)
#pragma unroll
        for (int c = 0; c < 7; c++) acc[c] += __shfl_xor(acc[c], off);
    if (lane == 0) {
#pragma unroll
        for (int c = 0; c < 7; c++) out[(size_t)row*7 + c] = acc[c] + bc[c];
    }
}

extern "C" void kernel_launch(void* const* d_in, const int* in_sizes, int n_in,
                              void* d_out, int out_size, void* d_ws, size_t ws_size,
                              hipStream_t stream) {
    (void)in_sizes; (void)n_in; (void)out_size; (void)ws_size;
    const float* text   = (const float*)d_in[0];
    const float* audio  = (const float*)d_in[1];
    const float* visual = (const float*)d_in[2];
    const float* spg    = (const float*)d_in[3];
    const float* tmg    = (const float*)d_in[4];
    const float* gW     = (const float*)d_in[6];
    const float* gb     = (const float*)d_in[7];
    const float* W0     = (const float*)d_in[8];
    const float* b0     = (const float*)d_in[9];
    const float* W1     = (const float*)d_in[10];
    const float* b1     = (const float*)d_in[11];
    const float* W2     = (const float*)d_in[12];
    const float* b2     = (const float*)d_in[13];
    const float* Wc     = (const float*)d_in[14];
    const float* bc     = (const float*)d_in[15];

    char* ws = (char*)d_ws;
    f16*   Wg1t = (f16*)(ws + OFF_WG1T);
    f16*   Wg2t = (f16*)(ws + OFF_WG2T);
    f16*   W0t  = (f16*)(ws + OFF_W0T);
    f16*   W1t  = (f16*)(ws + OFF_W1T);
    f16*   W2t  = (f16*)(ws + OFF_W2T);
    float* went = (float*)(ws + OFF_WENT);
    float* ents = (float*)(ws + OFF_ENTS);
    float* dsi  = (float*)(ws + OFF_DSI);
    f16*   xf   = (f16*)(ws + OFF_XF16);
    f16*   an   = (f16*)(ws + OFF_ANORM);
    f16*   hn   = (f16*)(ws + OFF_HN);
    f16*   Tbuf = (f16*)(ws + OFF_T);
    f16*   yt   = (f16*)(ws + OFF_YT);
    f16*   hcat = (f16*)(ws + OFF_HCAT);
    float* outp = (float*)d_out;

    dim3 blk(256);
    // prep + elementwise
    k_prep<<<3072, blk, 0, stream>>>(gW, W0, W1, W2, Wg1t, Wg2t, W0t, W1t, W2t, went);
    k_ent<<<4096, blk, 0, stream>>>(text, audio, visual, xf, ents);
    k_dsi<<<4096, blk, 0, stream>>>(spg, tmg, dsi);

    // T = Fsum @ Wg2 -> f16 Tbuf
    k_gemm<0><<<dim3(128,4), blk, 0, stream>>>(xf + 3*PLANE, Wg2t, 512,
        nullptr, nullptr, nullptr, nullptr, nullptr, Tbuf, 0, nullptr);
    // gates -> Hcat (f16 feat multiplicand from xf planes)
    k_gemm<1><<<dim3(128,4), blk, 0, stream>>>(xf + 0*PLANE, Wg1t, 512,
        Tbuf, ents + 0*MQ, went, gb, xf + 0*PLANE, hcat, 0,    nullptr);
    k_gemm<1><<<dim3(128,4), blk, 0, stream>>>(xf + 1*PLANE, Wg1t, 512,
        Tbuf, ents + 1*MQ, went, gb, xf + 1*PLANE, hcat, 512,  nullptr);
    k_gemm<1><<<dim3(128,4), blk, 0, stream>>>(xf + 2*PLANE, Wg1t, 512,
        Tbuf, ents + 2*MQ, went, gb, xf + 2*PLANE, hcat, 1024, nullptr);

    // norm_adj (aliases XF16 planes 0-1 — safe now that gates are done)
    k_anorm<<<16384, blk, 0, stream>>>(spg, tmg, dsi, an);

    // layer 0
    k_gemm<2><<<dim3(128,4), blk, 0, stream>>>(hcat, W0t, 1536,
        nullptr, nullptr, nullptr, nullptr, nullptr, yt, 0, nullptr);
    k_gemm<3><<<dim3(8,4,16), blk, 0, stream>>>(an, yt, 1024,
        nullptr, nullptr, nullptr, nullptr, nullptr, hn, 0, b0);
    // layer 1
    k_gemm<2><<<dim3(128,4), blk, 0, stream>>>(hn, W1t, 512,
        nullptr, nullptr, nullptr, nullptr, nullptr, yt, 0, nullptr);
    k_gemm<3><<<dim3(8,4,16), blk, 0, stream>>>(an, yt, 1024,
        nullptr, nullptr, nullptr, nullptr, nullptr, hn, 0, b1);
    // layer 2
    k_gemm<2><<<dim3(128,4), blk, 0, stream>>>(hn, W2t, 512,
        nullptr, nullptr, nullptr, nullptr, nullptr, yt, 0, nullptr);
    k_gemm<3><<<dim3(8,4,16), blk, 0, stream>>>(an, yt, 1024,
        nullptr, nullptr, nullptr, nullptr, nullptr, hn, 0, b2);

    // classifier
    k_cls<<<4096, blk, 0, stream>>>(hn, Wc, bc, outp);
}